// Round 7
// baseline (206.512 us; speedup 1.0000x reference)
//
#include <hip/hip_runtime.h>
#include <stdint.h>

#define SEQ 3072
#define NH  16
#define DH  64
#define WQ  32               // q rows per wave (fixed by 32x32 MFMA)
#define QBLK 64              // q rows per block (2 q-subtiles)
#define KVBLK 64
#define NKT (SEQ / KVBLK)    // 48
#define HALF_T (NKT / 2)     // 24 kv tiles per kv-half
#define NQB (SEQ / QBLK)     // 48
#define NWORDS (SEQ * SEQ / 64)

typedef __attribute__((ext_vector_type(8))) __bf16 bf16x8;
typedef __attribute__((ext_vector_type(16))) float f32x16;

union BF8 { ushort us[8]; uint u[4]; uint4 u4; bf16x8 v; };

__device__ __forceinline__ ushort f2bf(float f) {
    uint u = __builtin_bit_cast(uint, f);
    return (ushort)((u + 0x7FFFu + ((u >> 16) & 1u)) >> 16);
}

// ---------------- mask dtype detection ----------------
__global__ void detect_kernel(const uint32_t* __restrict__ m, int* __restrict__ flag) {
    __shared__ int cntA, cntB;
    if (threadIdx.x == 0) { cntA = 0; cntB = 0; }
    __syncthreads();
    int a = 0, b = 0;
    for (int i = 0; i < 16; ++i) {
        uint32_t w = m[threadIdx.x + i * 256];
        if (w & 0xFFFFFF00u) a = 1;
        if (w & 0x0000FFFFu) b = 1;
    }
    if (a) atomicOr(&cntA, 1);
    if (b) atomicOr(&cntB, 1);
    __syncthreads();
    if (threadIdx.x == 0) *flag = (cntA == 0) ? 1 : ((cntB == 0) ? 2 : 0);
}

// ---------------- mask -> transposed bitmask: bits2[kword*SEQ + qrow] ----------------
__global__ void pack_kernel(const void* __restrict__ mask, const int* __restrict__ flag,
                            uint64_t* __restrict__ bits) {
    int g = blockIdx.x * 256 + threadIdx.x;
    int f = *flag;
    bool v;
    if (f == 1)      v = ((const int*)mask)[g] != 0;
    else if (f == 2) v = ((const float*)mask)[g] != 0.0f;
    else             v = ((const unsigned char*)mask)[g] != 0;
    uint64_t b = __ballot(v);
    if ((threadIdx.x & 63) == 0) {
        int w = g >> 6;
        int qrow = w / NKT, cw = w % NKT;
        bits[(size_t)cw * SEQ + qrow] = b;
    }
}

// ---------------- Q convert: fp32 -> bf16, scale*log2(e) folded ----------------
#define SCALE_Q (0.125f * 1.44269504f)
__global__ void convert_q(const float* __restrict__ Q, ushort* __restrict__ Qb) {
    int i = (blockIdx.x * 256 + threadIdx.x) * 8;
    float4 a = *(const float4*)(Q + i);
    float4 b = *(const float4*)(Q + i + 4);
    BF8 t;
    t.us[0] = f2bf(a.x * SCALE_Q); t.us[1] = f2bf(a.y * SCALE_Q);
    t.us[2] = f2bf(a.z * SCALE_Q); t.us[3] = f2bf(a.w * SCALE_Q);
    t.us[4] = f2bf(b.x * SCALE_Q); t.us[5] = f2bf(b.y * SCALE_Q);
    t.us[6] = f2bf(b.z * SCALE_Q); t.us[7] = f2bf(b.w * SCALE_Q);
    *(uint4*)(Qb + i) = t.u4;
}

// ---------------- K/V convert+swizzle pre-pass ----------------
// K tile: chunk ch = row*8 + f' holds K[row][(f'^(row&7))*8 + 0..7]
// Vt tile: chunk ch = d*8 + f'  holds V[(f'^(d&7))*8 + 0..7][d]
__global__ __launch_bounds__(256)
void convert_kv(const float* __restrict__ K, const float* __restrict__ V,
                ushort* __restrict__ Kbz, ushort* __restrict__ Vtz) {
    const int kt = blockIdx.x, h = blockIdx.y;
    const int tid = threadIdx.x;
    __shared__ float Vf[64][68];

    {
        const int kr = tid >> 2, dc = (tid & 3) * 16;
        const float* vsrc = V + (((size_t)(kt * KVBLK + kr) * NH + h) * DH + dc);
        #pragma unroll
        for (int j = 0; j < 4; ++j) {
            float4 t = *(const float4*)(vsrc + 4 * j);
            Vf[kr][dc + 4 * j + 0] = t.x; Vf[kr][dc + 4 * j + 1] = t.y;
            Vf[kr][dc + 4 * j + 2] = t.z; Vf[kr][dc + 4 * j + 3] = t.w;
        }
    }

    ushort* kout = Kbz + ((size_t)(h * NKT + kt)) * 4096;
    #pragma unroll
    for (int i = 0; i < 2; ++i) {
        const int ch = tid + 256 * i;
        const int r = ch >> 3, fp = ch & 7;
        const float* ks = K + (((size_t)(kt * KVBLK + r) * NH + h) * DH + (fp ^ (r & 7)) * 8);
        float4 a = *(const float4*)(ks);
        float4 b = *(const float4*)(ks + 4);
        BF8 t;
        t.us[0] = f2bf(a.x); t.us[1] = f2bf(a.y); t.us[2] = f2bf(a.z); t.us[3] = f2bf(a.w);
        t.us[4] = f2bf(b.x); t.us[5] = f2bf(b.y); t.us[6] = f2bf(b.z); t.us[7] = f2bf(b.w);
        *(uint4*)(kout + ch * 8) = t.u4;
    }

    __syncthreads();

    ushort* vout = Vtz + ((size_t)(h * NKT + kt)) * 4096;
    #pragma unroll
    for (int i = 0; i < 2; ++i) {
        const int ch = tid + 256 * i;
        const int d = ch >> 3, fp = ch & 7;
        const int kc = fp ^ (d & 7);
        BF8 t;
        #pragma unroll
        for (int j = 0; j < 8; ++j)
            t.us[j] = f2bf(Vf[kc * 8 + j][d]);
        *(uint4*)(vout + ch * 8) = t.u4;
    }
}

// ---------------- MFMA flash attention: KV-split blocks, in-register softmax ----------------
// Block = 64 q-rows; waves: (qsub = wv&1) x (kvhalf = wv>>1). Each wave: 32 q x 24 kv-tiles.
// S = mfma(A=K, B=Q): D col = lane&31 = q; O = mfma(A=P, B=Vt): D col = lane&31 = d.
// Per-lane l_ is a HALF-row partial (lanes lq / lq+32 complementary) -> must permlane-reduce
// before the merge (this was the R6 bug).
__global__ __launch_bounds__(256, 3)
void attn6(const ushort* __restrict__ Qb, const ushort* __restrict__ Kbz,
           const ushort* __restrict__ Vtz, const uint64_t* __restrict__ bits2,
           float* __restrict__ out)
{
    const int bid = blockIdx.x;
    const int swz = (bid & 7) * (NQB * NH / 8) + (bid >> 3);   // 768 blocks, 96/XCD (2 heads)
    const int h = swz / NQB, qt = swz % NQB;
    const int tid = threadIdx.x;
    const int wv = tid >> 6, lane = tid & 63;
    const int qsub = wv & 1, kvh = wv >> 1;
    const int lq = lane & 31, hh = lane >> 5;
    const int qrow0 = qt * QBLK + qsub * WQ;
    const int p = tid & 127;              // pair-local staging id (2 waves per kv-half)

    __shared__ __align__(16) ushort SMEM[16384];     // 32 KB: K halves [0,8K), V halves [8K,16K)
    ushort* Kb = SMEM + kvh * 4096;
    ushort* Vt = SMEM + 8192 + kvh * 4096;

    // Q B-frags: qf[kc] = Q[qrow0+lq][kc*16 + hh*8 + j]
    bf16x8 qf[4];
    {
        const ushort* qp = Qb + ((size_t)(qrow0 + lq) * NH + h) * DH;
        #pragma unroll
        for (int kc = 0; kc < 4; ++kc)
            qf[kc] = *(const bf16x8*)(qp + kc * 16 + hh * 8);
    }

    f32x16 o0, o1;
    #pragma unroll
    for (int i = 0; i < 16; ++i) { o0[i] = 0.f; o1[i] = 0.f; }
    float m_ = 0.0f, l_ = 0.0f;   // log2 domain, deferred max

    const int kt0 = kvh * HALF_T;
    const ushort* ktile = Kbz + ((size_t)(h * NKT + kt0)) * 4096;
    const ushort* vtile = Vtz + ((size_t)(h * NKT + kt0)) * 4096;

    uint4 kreg[4], vreg[4];
    #pragma unroll
    for (int i = 0; i < 4; ++i) {
        kreg[i] = *(const uint4*)(ktile + (size_t)(p + 128 * i) * 8);
        vreg[i] = *(const uint4*)(vtile + (size_t)(p + 128 * i) * 8);
    }
    #pragma unroll
    for (int i = 0; i < 4; ++i) {
        *(uint4*)&Kb[(p + 128 * i) * 8] = kreg[i];
        *(uint4*)&Vt[(p + 128 * i) * 8] = vreg[i];
    }
    __syncthreads();

    for (int it = 0; it < HALF_T; ++it) {
        // T14: issue next-tile global loads early (land during compute)
        if (it + 1 < HALF_T) {
            const ushort* kn = ktile + (size_t)(it + 1) * 4096;
            const ushort* vn = vtile + (size_t)(it + 1) * 4096;
            #pragma unroll
            for (int i = 0; i < 4; ++i) {
                kreg[i] = *(const uint4*)(kn + (size_t)(p + 128 * i) * 8);
                vreg[i] = *(const uint4*)(vn + (size_t)(p + 128 * i) * 8);
            }
        }
        const uint64_t mw = bits2[(size_t)(kt0 + it) * SEQ + qrow0 + lq];

        // ---- QK^T ----
        f32x16 s0, s1;
        #pragma unroll
        for (int i = 0; i < 16; ++i) { s0[i] = 0.f; s1[i] = 0.f; }
        __builtin_amdgcn_s_setprio(1);
        #pragma unroll
        for (int kc = 0; kc < 4; ++kc) {
            const int f0 = (hh + 2 * kc) ^ (lq & 7);
            bf16x8 k0 = *(const bf16x8*)&Kb[lq * 64 + f0 * 8];
            s0 = __builtin_amdgcn_mfma_f32_32x32x16_bf16(k0, qf[kc], s0, 0, 0, 0);
            bf16x8 k1 = *(const bf16x8*)&Kb[(lq + 32) * 64 + f0 * 8];
            s1 = __builtin_amdgcn_mfma_f32_32x32x16_bf16(k1, qf[kc], s1, 0, 0, 0);
        }
        __builtin_amdgcn_s_setprio(0);

        // ---- in-register softmax (per-lane q = lq) ----
        const uint64_t mu = mw >> (4 * hh);
        const uint mlo = (uint)mu, mhi = (uint)(mu >> 32);

        float pm = -1e30f;
        #pragma unroll
        for (int i = 0; i < 16; ++i) pm = fmaxf(pm, fmaxf(s0[i], s1[i]));
        {
            float a = pm, b = pm;
            asm("v_permlane32_swap_b32 %0, %1" : "+v"(a), "+v"(b));
            pm = fmaxf(a, b);
        }

        // T13 defer-max (rare path; scores in log2 units, max ~7 < 12)
        if (__any(pm > m_ + 12.0f)) {
            const float mnew = fmaxf(m_, pm);
            const float alpha = __builtin_amdgcn_exp2f(m_ - mnew);
            l_ *= alpha;
            #pragma unroll
            for (int r = 0; r < 16; ++r) {
                const int q_r = (r & 3) + 8 * (r >> 2) + 4 * hh;
                const float ar = __shfl(alpha, q_r);
                o0[r] *= ar; o1[r] *= ar;
            }
            m_ = mnew;
        }

        // p = exp2(s - m) * maskbit
        float lacc = 0.f;
        #pragma unroll
        for (int r = 0; r < 16; ++r) {
            const int sh = (r & 3) + 8 * (r >> 2);
            float p0 = __builtin_amdgcn_exp2f(s0[r] - m_);
            p0 = ((mlo >> sh) & 1u) ? p0 : 0.f;
            float p1 = __builtin_amdgcn_exp2f(s1[r] - m_);
            p1 = ((mhi >> sh) & 1u) ? p1 : 0.f;
            s0[r] = p0; s1[r] = p1;
            lacc += p0 + p1;
        }
        l_ += lacc;

        // ---- T12: P -> bf16 A-frags via cvt_pk + permlane32_swap ----
        bf16x8 pa[4];
        {
            #define PKSWAP(dlo, dhi, a0, a1, b0, b1)                                   \
                {   uint wl, wh;                                                       \
                    asm("v_cvt_pk_bf16_f32 %0, %1, %2" : "=v"(wl) : "v"(a0), "v"(a1)); \
                    asm("v_cvt_pk_bf16_f32 %0, %1, %2" : "=v"(wh) : "v"(b0), "v"(b1)); \
                    asm("v_permlane32_swap_b32 %0, %1" : "+v"(wl), "+v"(wh));          \
                    dlo = wl; dhi = wh; }
            BF8 t0, t1, t2, t3;
            PKSWAP(t0.u[0], t0.u[2], s0[0],  s0[1],  s0[4],  s0[5]);
            PKSWAP(t0.u[1], t0.u[3], s0[2],  s0[3],  s0[6],  s0[7]);
            PKSWAP(t1.u[0], t1.u[2], s0[8],  s0[9],  s0[12], s0[13]);
            PKSWAP(t1.u[1], t1.u[3], s0[10], s0[11], s0[14], s0[15]);
            PKSWAP(t2.u[0], t2.u[2], s1[0],  s1[1],  s1[4],  s1[5]);
            PKSWAP(t2.u[1], t2.u[3], s1[2],  s1[3],  s1[6],  s1[7]);
            PKSWAP(t3.u[0], t3.u[2], s1[8],  s1[9],  s1[12], s1[13]);
            PKSWAP(t3.u[1], t3.u[3], s1[10], s1[11], s1[14], s1[15]);
            pa[0] = t0.v; pa[1] = t1.v; pa[2] = t2.v; pa[3] = t3.v;
            #undef PKSWAP
        }

        // ---- PV ----
        __builtin_amdgcn_s_setprio(1);
        #pragma unroll
        for (int kc = 0; kc < 4; ++kc) {
            const int f0 = (hh + 2 * kc) ^ (lq & 7);
            bf16x8 v0 = *(const bf16x8*)&Vt[lq * 64 + f0 * 8];
            o0 = __builtin_amdgcn_mfma_f32_32x32x16_bf16(pa[kc], v0, o0, 0, 0, 0);
            bf16x8 v1 = *(const bf16x8*)&Vt[(lq + 32) * 64 + f0 * 8];
            o1 = __builtin_amdgcn_mfma_f32_32x32x16_bf16(pa[kc], v1, o1, 0, 0, 0);
        }
        __builtin_amdgcn_s_setprio(0);

        __syncthreads();   // all reads of this tile done (both halves)
        if (it + 1 < HALF_T) {
            #pragma unroll
            for (int i = 0; i < 4; ++i) {
                *(uint4*)&Kb[(p + 128 * i) * 8] = kreg[i];
                *(uint4*)&Vt[(p + 128 * i) * 8] = vreg[i];
            }
        }
        __syncthreads();   // writes visible
    }

    // ---- R6 BUG FIX: cross-half l reduction (lanes lq / lq+32 hold complementary partials)
    {
        float a = l_, b = l_;
        asm("v_permlane32_swap_b32 %0, %1" : "+v"(a), "+v"(b));
        l_ = a + b;
    }

    // ---- merge kv-halves through LDS (aliases K/V buffers; safe after final barriers) ----
    // Layout per qsub: float area [64][36] for oB ([d][q], 36-padded) + mB[32] + lB[32]
    float* LMq = (float*)SMEM + qsub * 2368;
    if (kvh == 1) {
        if (hh == 0) { LMq[64 * 36 + lq] = m_; LMq[64 * 36 + 32 + lq] = l_; }
        #pragma unroll
        for (int j = 0; j < 4; ++j) {
            float4 t0, t1;
            t0.x = o0[4 * j]; t0.y = o0[4 * j + 1]; t0.z = o0[4 * j + 2]; t0.w = o0[4 * j + 3];
            t1.x = o1[4 * j]; t1.y = o1[4 * j + 1]; t1.z = o1[4 * j + 2]; t1.w = o1[4 * j + 3];
            *(float4*)&LMq[lq * 36 + 4 * hh + 8 * j]        = t0;
            *(float4*)&LMq[(lq + 32) * 36 + 4 * hh + 8 * j] = t1;
        }
    }
    __syncthreads();
    if (kvh == 0) {
        const float mB = LMq[64 * 36 + lq], lB = LMq[64 * 36 + 32 + lq];
        const float mN = fmaxf(m_, mB);
        float cA = __builtin_amdgcn_exp2f(m_ - mN);
        float cB = __builtin_amdgcn_exp2f(mB - mN);
        const float l = l_ * cA + lB * cB;
        const float inv = (l > 0.f) ? 1.0f / l : 0.f;
        cA *= inv; cB *= inv;
        #pragma unroll
        for (int r = 0; r < 16; ++r) {
            const int q_r = (r & 3) + 8 * (r >> 2) + 4 * hh;
            const float a = __shfl(cA, q_r);
            const float b = __shfl(cB, q_r);
            float* op = out + ((size_t)(qrow0 + q_r) * NH + h) * DH;
            op[lq]      = o0[r] * a + LMq[lq * 36 + q_r] * b;
            op[lq + 32] = o1[r] * a + LMq[(lq + 32) * 36 + q_r] * b;
        }
    }
}

// ---------------- fallback (direct int32 mask; only if ws too small) ----------------
__global__ __launch_bounds__(256, 2)
void attn_fb(const float* __restrict__ Q, const float* __restrict__ K,
             const float* __restrict__ V, const int* __restrict__ mask_i32,
             float* __restrict__ out)
{
    const int qtile = blockIdx.x, h = blockIdx.y;
    const int tid  = threadIdx.x;
    const int wv   = tid >> 6, lane = tid & 63;
    const int g    = lane >> 4, c = lane & 15;
    const int qb   = qtile * 64 + wv * 16;

    typedef __attribute__((ext_vector_type(4))) float f32x4;
    __shared__ __align__(16) ushort KbS[KVBLK * 72];
    __shared__ __align__(16) ushort VtS[DH * 72];
    __shared__ __align__(16) ushort PbS[4 * 16 * 72];
    ushort* Pw = &PbS[wv * 16 * 72];

    bf16x8 qa[2];
    {
        const float* qp = Q + ((qb + c) * NH + h) * DH;
        #pragma unroll
        for (int kk = 0; kk < 2; ++kk) {
            BF8 t;
            const float4* pp = (const float4*)(qp + kk * 32 + g * 8);
            float4 f0 = pp[0], f1 = pp[1];
            t.us[0] = f2bf(f0.x * 0.125f); t.us[1] = f2bf(f0.y * 0.125f);
            t.us[2] = f2bf(f0.z * 0.125f); t.us[3] = f2bf(f0.w * 0.125f);
            t.us[4] = f2bf(f1.x * 0.125f); t.us[5] = f2bf(f1.y * 0.125f);
            t.us[6] = f2bf(f1.z * 0.125f); t.us[7] = f2bf(f1.w * 0.125f);
            qa[kk] = t.v;
        }
    }

    f32x4 oacc[4];
    float m_[4], lsum[4];
    #pragma unroll
    for (int nt = 0; nt < 4; ++nt) oacc[nt] = (f32x4){0.f, 0.f, 0.f, 0.f};
    #pragma unroll
    for (int r = 0; r < 4; ++r) { m_[r] = -1e30f; lsum[r] = 0.f; }

    const int srow0 = tid >> 3;
    const int fch   = tid & 7;

    for (int kt = 0; kt < NKT; ++kt) {
        __syncthreads();
        #pragma unroll
        for (int i = 0; i < 2; ++i) {
            const int krow = srow0 + 32 * i;
            const int gofs = ((kt * KVBLK + krow) * NH + h) * DH + fch * 8;
            const float4* kp = (const float4*)(K + gofs);
            const float4* vp = (const float4*)(V + gofs);
            float4 k0 = kp[0], k1 = kp[1];
            float4 v0 = vp[0], v1 = vp[1];
            BF8 kb;
            kb.us[0] = f2bf(k0.x); kb.us[1] = f2bf(k0.y);
            kb.us[2] = f2bf(k0.z); kb.us[3] = f2bf(k0.w);
            kb.us[4] = f2bf(k1.x); kb.us[5] = f2bf(k1.y);
            kb.us[6] = f2bf(k1.z); kb.us[7] = f2bf(k1.w);
            *(uint4*)&KbS[krow * 72 + (fch ^ (krow & 7)) * 8] = kb.u4;
            float vf[8] = {v0.x, v0.y, v0.z, v0.w, v1.x, v1.y, v1.z, v1.w};
            #pragma unroll
            for (int j = 0; j < 8; ++j) {
                const int d = fch * 8 + j;
                VtS[d * 72 + ((krow >> 3) ^ ((d >> 3) & 7)) * 8 + (krow & 7)] = f2bf(vf[j]);
            }
        }
        __syncthreads();

        f32x4 sacc[4];
        #pragma unroll
        for (int nt = 0; nt < 4; ++nt) sacc[nt] = (f32x4){0.f, 0.f, 0.f, 0.f};
        #pragma unroll
        for (int kk = 0; kk < 2; ++kk) {
            #pragma unroll
            for (int nt = 0; nt < 4; ++nt) {
                const int krow = nt * 16 + c;
                bf16x8 kf = *(const bf16x8*)&KbS[krow * 72 + (((g + 4 * kk) ^ (krow & 7))) * 8];
                sacc[nt] = __builtin_amdgcn_mfma_f32_16x16x32_bf16(qa[kk], kf, sacc[nt], 0, 0, 0);
            }
        }

        float pmax[4];
        #pragma unroll
        for (int r = 0; r < 4; ++r) pmax[r] = -1e30f;
        #pragma unroll
        for (int nt = 0; nt < 4; ++nt) {
            #pragma unroll
            for (int r = 0; r < 4; ++r) {
                bool keep = mask_i32[(size_t)(qb + 4 * g + r) * SEQ + kt * KVBLK + nt * 16 + c] != 0;
                float s = keep ? sacc[nt][r] : -1e30f;
                sacc[nt][r] = s;
                pmax[r] = fmaxf(pmax[r], s);
            }
        }
        #pragma unroll
        for (int r = 0; r < 4; ++r) {
            float v = pmax[r];
            v = fmaxf(v, __shfl_xor(v, 1));
            v = fmaxf(v, __shfl_xor(v, 2));
            v = fmaxf(v, __shfl_xor(v, 4));
            v = fmaxf(v, __shfl_xor(v, 8));
            float nm = fmaxf(m_[r], v);
            float alpha = __expf(m_[r] - nm);
            m_[r] = nm;
            lsum[r] *= alpha;
            #pragma unroll
            for (int nt = 0; nt < 4; ++nt) oacc[nt][r] *= alpha;
        }
        #pragma unroll
        for (int nt = 0; nt < 4; ++nt) {
            #pragma unroll
            for (int r = 0; r < 4; ++r) {
                float pv = __expf(sacc[nt][r] - m_[r]);
                lsum[r] += pv;
                const int row = 4 * g + r, col = nt * 16 + c;
                Pw[row * 72 + (((col >> 3) ^ (row & 7))) * 8 + (col & 7)] = f2bf(pv);
            }
        }
        #pragma unroll
        for (int kk = 0; kk < 2; ++kk) {
            bf16x8 pa = *(const bf16x8*)&Pw[c * 72 + (((g + 4 * kk) ^ (c & 7))) * 8];
            #pragma unroll
            for (int nt = 0; nt < 4; ++nt) {
                const int d = nt * 16 + c;
                bf16x8 vb = *(const bf16x8*)&VtS[d * 72 + (((g + 4 * kk) ^ ((d >> 3) & 7))) * 8];
                oacc[nt] = __builtin_amdgcn_mfma_f32_16x16x32_bf16(pa, vb, oacc[nt], 0, 0, 0);
            }
        }
    }

    #pragma unroll
    for (int r = 0; r < 4; ++r) {
        float v = lsum[r];
        v += __shfl_xor(v, 1); v += __shfl_xor(v, 2);
        v += __shfl_xor(v, 4); v += __shfl_xor(v, 8);
        lsum[r] = (v > 0.f) ? 1.0f / v : 0.f;
    }
    #pragma unroll
    for (int nt = 0; nt < 4; ++nt) {
        #pragma unroll
        for (int r = 0; r < 4; ++r) {
            out[((qb + 4 * g + r) * NH + h) * DH + nt * 16 + c] = oacc[nt][r] * lsum[r];
        }
    }
}

extern "C" void kernel_launch(void* const* d_in, const int* in_sizes, int n_in,
                              void* d_out, int out_size, void* d_ws, size_t ws_size,
                              hipStream_t stream) {
    const float* Q    = (const float*)d_in[0];
    const float* K    = (const float*)d_in[1];
    const float* V    = (const float*)d_in[2];
    const void*  mask = d_in[3];
    float* out = (float*)d_out;

    const size_t off_bits = 64;
    const size_t off_qb   = off_bits + (size_t)NWORDS * 8;
    const size_t off_kbz  = off_qb  + (size_t)SEQ * NH * DH * 2;
    const size_t off_vtz  = off_kbz + (size_t)SEQ * NH * DH * 2;
    const size_t need     = off_vtz + (size_t)SEQ * NH * DH * 2;

    if (ws_size >= need) {
        int*      flag = (int*)d_ws;
        uint64_t* bits = (uint64_t*)((char*)d_ws + off_bits);
        ushort*   Qb   = (ushort*)((char*)d_ws + off_qb);
        ushort*   Kbz  = (ushort*)((char*)d_ws + off_kbz);
        ushort*   Vtz  = (ushort*)((char*)d_ws + off_vtz);
        detect_kernel<<<1, 256, 0, stream>>>((const uint32_t*)mask, flag);
        pack_kernel<<<SEQ * SEQ / 256, 256, 0, stream>>>(mask, flag, bits);
        convert_q<<<SEQ * NH * DH / (256 * 8), 256, 0, stream>>>(Q, Qb);
        convert_kv<<<dim3(NKT, NH), 256, 0, stream>>>(K, V, Kbz, Vtz);
        attn6<<<NQB * NH, 256, 0, stream>>>(Qb, Kbz, Vtz, bits, out);
    } else {
        attn_fb<<<dim3(NKT, NH), 256, 0, stream>>>(Q, K, V, (const int*)mask, out);
    }
}

// Round 8
// 110.625 us; speedup vs baseline: 1.8668x; 1.8668x over previous
//
#include <hip/hip_runtime.h>
#include <stdint.h>

#define SEQ 3072
#define NH  16
#define DH  64
#define WQ  32               // q rows per wave (fixed by 32x32 MFMA)
#define QBLK 64              // q rows per block (2 q-subtiles)
#define KVBLK 64
#define NKT (SEQ / KVBLK)    // 48
#define HALF_T (NKT / 2)     // 24 kv tiles per kv-half
#define NQB (SEQ / QBLK)     // 48
#define NWORDS (SEQ * SEQ / 64)

typedef __attribute__((ext_vector_type(8))) __bf16 bf16x8;
typedef __attribute__((ext_vector_type(16))) float f32x16;

union BF8 { ushort us[8]; uint u[4]; uint4 u4; bf16x8 v; };

__device__ __forceinline__ ushort f2bf(float f) {
    uint u = __builtin_bit_cast(uint, f);
    return (ushort)((u + 0x7FFFu + ((u >> 16) & 1u)) >> 16);
}

// async global->LDS DMA, 16B per lane; LDS dest = uniform base + lane*16
__device__ __forceinline__ void gload_lds16(const void* g, void* l) {
    __builtin_amdgcn_global_load_lds(
        (const __attribute__((address_space(1))) unsigned int*)g,
        (__attribute__((address_space(3))) unsigned int*)l,
        16, 0, 0);
}

// ---------------- mask dtype detection ----------------
__global__ void detect_kernel(const uint32_t* __restrict__ m, int* __restrict__ flag) {
    __shared__ int cntA, cntB;
    if (threadIdx.x == 0) { cntA = 0; cntB = 0; }
    __syncthreads();
    int a = 0, b = 0;
    for (int i = 0; i < 16; ++i) {
        uint32_t w = m[threadIdx.x + i * 256];
        if (w & 0xFFFFFF00u) a = 1;
        if (w & 0x0000FFFFu) b = 1;
    }
    if (a) atomicOr(&cntA, 1);
    if (b) atomicOr(&cntB, 1);
    __syncthreads();
    if (threadIdx.x == 0) *flag = (cntA == 0) ? 1 : ((cntB == 0) ? 2 : 0);
}

// ---------------- mask -> transposed bitmask: bits2[kword*SEQ + qrow] ----------------
__global__ void pack_kernel(const void* __restrict__ mask, const int* __restrict__ flag,
                            uint64_t* __restrict__ bits) {
    int g = blockIdx.x * 256 + threadIdx.x;
    int f = *flag;
    bool v;
    if (f == 1)      v = ((const int*)mask)[g] != 0;
    else if (f == 2) v = ((const float*)mask)[g] != 0.0f;
    else             v = ((const unsigned char*)mask)[g] != 0;
    uint64_t b = __ballot(v);
    if ((threadIdx.x & 63) == 0) {
        int w = g >> 6;
        int qrow = w / NKT, cw = w % NKT;
        bits[(size_t)cw * SEQ + qrow] = b;
    }
}

// ---------------- Q convert: fp32 -> bf16, scale*log2(e) folded ----------------
#define SCALE_Q (0.125f * 1.44269504f)
__global__ void convert_q(const float* __restrict__ Q, ushort* __restrict__ Qb) {
    int i = (blockIdx.x * 256 + threadIdx.x) * 8;
    float4 a = *(const float4*)(Q + i);
    float4 b = *(const float4*)(Q + i + 4);
    BF8 t;
    t.us[0] = f2bf(a.x * SCALE_Q); t.us[1] = f2bf(a.y * SCALE_Q);
    t.us[2] = f2bf(a.z * SCALE_Q); t.us[3] = f2bf(a.w * SCALE_Q);
    t.us[4] = f2bf(b.x * SCALE_Q); t.us[5] = f2bf(b.y * SCALE_Q);
    t.us[6] = f2bf(b.z * SCALE_Q); t.us[7] = f2bf(b.w * SCALE_Q);
    *(uint4*)(Qb + i) = t.u4;
}

// ---------------- K/V convert+swizzle pre-pass ----------------
// K tile: chunk ch = row*8 + f' holds K[row][(f'^(row&7))*8 + 0..7]
// Vt tile: chunk ch = d*8 + f'  holds V[(f'^(d&7))*8 + 0..7][d]
__global__ __launch_bounds__(256)
void convert_kv(const float* __restrict__ K, const float* __restrict__ V,
                ushort* __restrict__ Kbz, ushort* __restrict__ Vtz) {
    const int kt = blockIdx.x, h = blockIdx.y;
    const int tid = threadIdx.x;
    __shared__ float Vf[64][68];

    {
        const int kr = tid >> 2, dc = (tid & 3) * 16;
        const float* vsrc = V + (((size_t)(kt * KVBLK + kr) * NH + h) * DH + dc);
        #pragma unroll
        for (int j = 0; j < 4; ++j) {
            float4 t = *(const float4*)(vsrc + 4 * j);
            Vf[kr][dc + 4 * j + 0] = t.x; Vf[kr][dc + 4 * j + 1] = t.y;
            Vf[kr][dc + 4 * j + 2] = t.z; Vf[kr][dc + 4 * j + 3] = t.w;
        }
    }

    ushort* kout = Kbz + ((size_t)(h * NKT + kt)) * 4096;
    #pragma unroll
    for (int i = 0; i < 2; ++i) {
        const int ch = tid + 256 * i;
        const int r = ch >> 3, fp = ch & 7;
        const float* ks = K + (((size_t)(kt * KVBLK + r) * NH + h) * DH + (fp ^ (r & 7)) * 8);
        float4 a = *(const float4*)(ks);
        float4 b = *(const float4*)(ks + 4);
        BF8 t;
        t.us[0] = f2bf(a.x); t.us[1] = f2bf(a.y); t.us[2] = f2bf(a.z); t.us[3] = f2bf(a.w);
        t.us[4] = f2bf(b.x); t.us[5] = f2bf(b.y); t.us[6] = f2bf(b.z); t.us[7] = f2bf(b.w);
        *(uint4*)(kout + ch * 8) = t.u4;
    }

    __syncthreads();

    ushort* vout = Vtz + ((size_t)(h * NKT + kt)) * 4096;
    #pragma unroll
    for (int i = 0; i < 2; ++i) {
        const int ch = tid + 256 * i;
        const int d = ch >> 3, fp = ch & 7;
        const int kc = fp ^ (d & 7);
        BF8 t;
        #pragma unroll
        for (int j = 0; j < 8; ++j)
            t.us[j] = f2bf(Vf[kc * 8 + j][d]);
        *(uint4*)(vout + ch * 8) = t.u4;
    }
}

// ---------------- MFMA flash attention: KV-split, global_load_lds dbuf staging ----------------
// Block = 64 q-rows; waves: (qsub = wv&1) x (kvhalf = wv>>1). Each wave: 32 q x 24 kv-tiles.
// Staging role: qsub==0 wave DMAs its half's K tile, qsub==1 wave DMAs the V tile.
// S = mfma(A=K, B=Q): D col = lane&31 = q; O = mfma(A=P, B=Vt): D col = lane&31 = d.
// Per-lane l_ is a HALF-row partial -> permlane-reduce before merge (R6 lesson).
__global__ __launch_bounds__(256, 2)
void attn8(const ushort* __restrict__ Qb, const ushort* __restrict__ Kbz,
           const ushort* __restrict__ Vtz, const uint64_t* __restrict__ bits2,
           float* __restrict__ out)
{
    const int bid = blockIdx.x;
    const int swz = (bid & 7) * (NQB * NH / 8) + (bid >> 3);   // 768 blocks, 96/XCD (2 heads)
    const int h = swz / NQB, qt = swz % NQB;
    const int tid = threadIdx.x;
    const int wv = tid >> 6, lane = tid & 63;
    const int qsub = wv & 1, kvh = wv >> 1;
    const int lq = lane & 31, hh = lane >> 5;
    const int qrow0 = qt * QBLK + qsub * WQ;

    __shared__ __align__(16) ushort KbS[2][2][4096];   // [buf][half][8KB tile] = 32 KB
    __shared__ __align__(16) ushort VtS[2][2][4096];   // 32 KB

    // Q B-frags: qf[kc] = Q[qrow0+lq][kc*16 + hh*8 + j]
    bf16x8 qf[4];
    {
        const ushort* qp = Qb + ((size_t)(qrow0 + lq) * NH + h) * DH;
        #pragma unroll
        for (int kc = 0; kc < 4; ++kc)
            qf[kc] = *(const bf16x8*)(qp + kc * 16 + hh * 8);
    }

    f32x16 o0, o1;
    #pragma unroll
    for (int i = 0; i < 16; ++i) { o0[i] = 0.f; o1[i] = 0.f; }
    float m_ = 0.0f, l_ = 0.0f;   // log2 domain, deferred max

    const int kt0 = kvh * HALF_T;
    // byte pointers to this half's tile sequence (pre-swizzled, 8192 B per tile)
    const char* gK = (const char*)(Kbz + ((size_t)(h * NKT + kt0)) * 4096);
    const char* gV = (const char*)(Vtz + ((size_t)(h * NKT + kt0)) * 4096);
    const char* gsrc0 = (qsub == 0) ? gK : gV;   // this wave's staging role

    // prologue: DMA tile 0 into buf 0
    {
        char* dst = (qsub == 0) ? (char*)&KbS[0][kvh][0] : (char*)&VtS[0][kvh][0];
        #pragma unroll
        for (int j = 0; j < 8; ++j)
            gload_lds16(gsrc0 + (size_t)j * 1024 + (size_t)lane * 16, dst + j * 1024);
    }
    __syncthreads();   // compiler drains vmcnt(0) before barrier -> tile 0 ready

    int cur = 0;
    for (int it = 0; it < HALF_T; ++it) {
        // issue next-tile DMA first: full compute phase hides the HBM latency
        if (it + 1 < HALF_T) {
            const char* src = gsrc0 + (size_t)(it + 1) * 8192;
            char* dst = (qsub == 0) ? (char*)&KbS[cur ^ 1][kvh][0]
                                    : (char*)&VtS[cur ^ 1][kvh][0];
            #pragma unroll
            for (int j = 0; j < 8; ++j)
                gload_lds16(src + (size_t)j * 1024 + (size_t)lane * 16, dst + j * 1024);
        }
        const uint64_t mw = bits2[(size_t)(kt0 + it) * SEQ + qrow0 + lq];
        const ushort* Kb = &KbS[cur][kvh][0];
        const ushort* Vt = &VtS[cur][kvh][0];

        // ---- QK^T ----
        f32x16 s0, s1;
        #pragma unroll
        for (int i = 0; i < 16; ++i) { s0[i] = 0.f; s1[i] = 0.f; }
        __builtin_amdgcn_s_setprio(1);
        #pragma unroll
        for (int kc = 0; kc < 4; ++kc) {
            const int f0 = (hh + 2 * kc) ^ (lq & 7);
            bf16x8 k0 = *(const bf16x8*)&Kb[lq * 64 + f0 * 8];
            s0 = __builtin_amdgcn_mfma_f32_32x32x16_bf16(k0, qf[kc], s0, 0, 0, 0);
            bf16x8 k1 = *(const bf16x8*)&Kb[(lq + 32) * 64 + f0 * 8];
            s1 = __builtin_amdgcn_mfma_f32_32x32x16_bf16(k1, qf[kc], s1, 0, 0, 0);
        }
        __builtin_amdgcn_s_setprio(0);

        // ---- in-register softmax (per-lane q = lq) ----
        const uint64_t mu = mw >> (4 * hh);
        const uint mlo = (uint)mu, mhi = (uint)(mu >> 32);

        float pm = -1e30f;
        #pragma unroll
        for (int i = 0; i < 16; ++i) pm = fmaxf(pm, fmaxf(s0[i], s1[i]));
        {
            float a = pm, b = pm;
            asm("v_permlane32_swap_b32 %0, %1" : "+v"(a), "+v"(b));
            pm = fmaxf(a, b);
        }

        // T13 defer-max (rare path; scores in log2 units)
        if (__any(pm > m_ + 12.0f)) {
            const float mnew = fmaxf(m_, pm);
            const float alpha = __builtin_amdgcn_exp2f(m_ - mnew);
            l_ *= alpha;
            #pragma unroll
            for (int r = 0; r < 16; ++r) {
                const int q_r = (r & 3) + 8 * (r >> 2) + 4 * hh;
                const float ar = __shfl(alpha, q_r);
                o0[r] *= ar; o1[r] *= ar;
            }
            m_ = mnew;
        }

        // p = exp2(s - m) * maskbit
        float lacc = 0.f;
        #pragma unroll
        for (int r = 0; r < 16; ++r) {
            const int sh = (r & 3) + 8 * (r >> 2);
            float p0 = __builtin_amdgcn_exp2f(s0[r] - m_);
            p0 = ((mlo >> sh) & 1u) ? p0 : 0.f;
            float p1 = __builtin_amdgcn_exp2f(s1[r] - m_);
            p1 = ((mhi >> sh) & 1u) ? p1 : 0.f;
            s0[r] = p0; s1[r] = p1;
            lacc += p0 + p1;
        }
        l_ += lacc;

        // ---- T12: P -> bf16 A-frags via cvt_pk + permlane32_swap ----
        bf16x8 pa[4];
        {
            #define PKSWAP(dlo, dhi, a0, a1, b0, b1)                                   \
                {   uint wl, wh;                                                       \
                    asm("v_cvt_pk_bf16_f32 %0, %1, %2" : "=v"(wl) : "v"(a0), "v"(a1)); \
                    asm("v_cvt_pk_bf16_f32 %0, %1, %2" : "=v"(wh) : "v"(b0), "v"(b1)); \
                    asm("v_permlane32_swap_b32 %0, %1" : "+v"(wl), "+v"(wh));          \
                    dlo = wl; dhi = wh; }
            BF8 t0, t1, t2, t3;
            PKSWAP(t0.u[0], t0.u[2], s0[0],  s0[1],  s0[4],  s0[5]);
            PKSWAP(t0.u[1], t0.u[3], s0[2],  s0[3],  s0[6],  s0[7]);
            PKSWAP(t1.u[0], t1.u[2], s0[8],  s0[9],  s0[12], s0[13]);
            PKSWAP(t1.u[1], t1.u[3], s0[10], s0[11], s0[14], s0[15]);
            PKSWAP(t2.u[0], t2.u[2], s1[0],  s1[1],  s1[4],  s1[5]);
            PKSWAP(t2.u[1], t2.u[3], s1[2],  s1[3],  s1[6],  s1[7]);
            PKSWAP(t3.u[0], t3.u[2], s1[8],  s1[9],  s1[12], s1[13]);
            PKSWAP(t3.u[1], t3.u[3], s1[10], s1[11], s1[14], s1[15]);
            pa[0] = t0.v; pa[1] = t1.v; pa[2] = t2.v; pa[3] = t3.v;
            #undef PKSWAP
        }

        // ---- PV ----
        __builtin_amdgcn_s_setprio(1);
        #pragma unroll
        for (int kc = 0; kc < 4; ++kc) {
            const int f0 = (hh + 2 * kc) ^ (lq & 7);
            bf16x8 v0 = *(const bf16x8*)&Vt[lq * 64 + f0 * 8];
            o0 = __builtin_amdgcn_mfma_f32_32x32x16_bf16(pa[kc], v0, o0, 0, 0, 0);
            bf16x8 v1 = *(const bf16x8*)&Vt[(lq + 32) * 64 + f0 * 8];
            o1 = __builtin_amdgcn_mfma_f32_32x32x16_bf16(pa[kc], v1, o1, 0, 0, 0);
        }
        __builtin_amdgcn_s_setprio(0);

        // one barrier per tile: drains this iter's DMA (next tile ready) and
        // orders reads-done before next iter's DMA overwrites buf cur^1... (dbuf: no WAR)
        __syncthreads();
        cur ^= 1;
    }

    // ---- cross-half l reduction (lanes lq / lq+32 hold complementary partials) ----
    {
        float a = l_, b = l_;
        asm("v_permlane32_swap_b32 %0, %1" : "+v"(a), "+v"(b));
        l_ = a + b;
    }

    // ---- merge kv-halves through LDS scratch (aliases KbS; safe after final barrier) ----
    // Layout per qsub: float area [64][36] for oB ([d][q], 36-padded) + mB[32] + lB[32]
    float* LMq = (float*)&KbS[0][0][0] + qsub * 2368;
    if (kvh == 1) {
        if (hh == 0) { LMq[64 * 36 + lq] = m_; LMq[64 * 36 + 32 + lq] = l_; }
        #pragma unroll
        for (int j = 0; j < 4; ++j) {
            float4 t0, t1;
            t0.x = o0[4 * j]; t0.y = o0[4 * j + 1]; t0.z = o0[4 * j + 2]; t0.w = o0[4 * j + 3];
            t1.x = o1[4 * j]; t1.y = o1[4 * j + 1]; t1.z = o1[4 * j + 2]; t1.w = o1[4 * j + 3];
            *(float4*)&LMq[lq * 36 + 4 * hh + 8 * j]        = t0;
            *(float4*)&LMq[(lq + 32) * 36 + 4 * hh + 8 * j] = t1;
        }
    }
    __syncthreads();
    if (kvh == 0) {
        const float mB = LMq[64 * 36 + lq], lB = LMq[64 * 36 + 32 + lq];
        const float mN = fmaxf(m_, mB);
        float cA = __builtin_amdgcn_exp2f(m_ - mN);
        float cB = __builtin_amdgcn_exp2f(mB - mN);
        const float l = l_ * cA + lB * cB;
        const float inv = (l > 0.f) ? 1.0f / l : 0.f;
        cA *= inv; cB *= inv;
        #pragma unroll
        for (int r = 0; r < 16; ++r) {
            const int q_r = (r & 3) + 8 * (r >> 2) + 4 * hh;
            const float a = __shfl(cA, q_r);
            const float b = __shfl(cB, q_r);
            float* op = out + ((size_t)(qrow0 + q_r) * NH + h) * DH;
            op[lq]      = o0[r] * a + LMq[lq * 36 + q_r] * b;
            op[lq + 32] = o1[r] * a + LMq[(lq + 32) * 36 + q_r] * b;
        }
    }
}

// ---------------- fallback (direct int32 mask; only if ws too small) ----------------
__global__ __launch_bounds__(256, 2)
void attn_fb(const float* __restrict__ Q, const float* __restrict__ K,
             const float* __restrict__ V, const int* __restrict__ mask_i32,
             float* __restrict__ out)
{
    const int qtile = blockIdx.x, h = blockIdx.y;
    const int tid  = threadIdx.x;
    const int wv   = tid >> 6, lane = tid & 63;
    const int g    = lane >> 4, c = lane & 15;
    const int qb   = qtile * 64 + wv * 16;

    typedef __attribute__((ext_vector_type(4))) float f32x4;
    __shared__ __align__(16) ushort KbS[KVBLK * 72];
    __shared__ __align__(16) ushort VtS[DH * 72];
    __shared__ __align__(16) ushort PbS[4 * 16 * 72];
    ushort* Pw = &PbS[wv * 16 * 72];

    bf16x8 qa[2];
    {
        const float* qp = Q + ((qb + c) * NH + h) * DH;
        #pragma unroll
        for (int kk = 0; kk < 2; ++kk) {
            BF8 t;
            const float4* pp = (const float4*)(qp + kk * 32 + g * 8);
            float4 f0 = pp[0], f1 = pp[1];
            t.us[0] = f2bf(f0.x * 0.125f); t.us[1] = f2bf(f0.y * 0.125f);
            t.us[2] = f2bf(f0.z * 0.125f); t.us[3] = f2bf(f0.w * 0.125f);
            t.us[4] = f2bf(f1.x * 0.125f); t.us[5] = f2bf(f1.y * 0.125f);
            t.us[6] = f2bf(f1.z * 0.125f); t.us[7] = f2bf(f1.w * 0.125f);
            qa[kk] = t.v;
        }
    }

    f32x4 oacc[4];
    float m_[4], lsum[4];
    #pragma unroll
    for (int nt = 0; nt < 4; ++nt) oacc[nt] = (f32x4){0.f, 0.f, 0.f, 0.f};
    #pragma unroll
    for (int r = 0; r < 4; ++r) { m_[r] = -1e30f; lsum[r] = 0.f; }

    const int srow0 = tid >> 3;
    const int fch   = tid & 7;

    for (int kt = 0; kt < NKT; ++kt) {
        __syncthreads();
        #pragma unroll
        for (int i = 0; i < 2; ++i) {
            const int krow = srow0 + 32 * i;
            const int gofs = ((kt * KVBLK + krow) * NH + h) * DH + fch * 8;
            const float4* kp = (const float4*)(K + gofs);
            const float4* vp = (const float4*)(V + gofs);
            float4 k0 = kp[0], k1 = kp[1];
            float4 v0 = vp[0], v1 = vp[1];
            BF8 kb;
            kb.us[0] = f2bf(k0.x); kb.us[1] = f2bf(k0.y);
            kb.us[2] = f2bf(k0.z); kb.us[3] = f2bf(k0.w);
            kb.us[4] = f2bf(k1.x); kb.us[5] = f2bf(k1.y);
            kb.us[6] = f2bf(k1.z); kb.us[7] = f2bf(k1.w);
            *(uint4*)&KbS[krow * 72 + (fch ^ (krow & 7)) * 8] = kb.u4;
            float vf[8] = {v0.x, v0.y, v0.z, v0.w, v1.x, v1.y, v1.z, v1.w};
            #pragma unroll
            for (int j = 0; j < 8; ++j) {
                const int d = fch * 8 + j;
                VtS[d * 72 + ((krow >> 3) ^ ((d >> 3) & 7)) * 8 + (krow & 7)] = f2bf(vf[j]);
            }
        }
        __syncthreads();

        f32x4 sacc[4];
        #pragma unroll
        for (int nt = 0; nt < 4; ++nt) sacc[nt] = (f32x4){0.f, 0.f, 0.f, 0.f};
        #pragma unroll
        for (int kk = 0; kk < 2; ++kk) {
            #pragma unroll
            for (int nt = 0; nt < 4; ++nt) {
                const int krow = nt * 16 + c;
                bf16x8 kf = *(const bf16x8*)&KbS[krow * 72 + (((g + 4 * kk) ^ (krow & 7))) * 8];
                sacc[nt] = __builtin_amdgcn_mfma_f32_16x16x32_bf16(qa[kk], kf, sacc[nt], 0, 0, 0);
            }
        }

        float pmax[4];
        #pragma unroll
        for (int r = 0; r < 4; ++r) pmax[r] = -1e30f;
        #pragma unroll
        for (int nt = 0; nt < 4; ++nt) {
            #pragma unroll
            for (int r = 0; r < 4; ++r) {
                bool keep = mask_i32[(size_t)(qb + 4 * g + r) * SEQ + kt * KVBLK + nt * 16 + c] != 0;
                float s = keep ? sacc[nt][r] : -1e30f;
                sacc[nt][r] = s;
                pmax[r] = fmaxf(pmax[r], s);
            }
        }
        #pragma unroll
        for (int r = 0; r < 4; ++r) {
            float v = pmax[r];
            v = fmaxf(v, __shfl_xor(v, 1));
            v = fmaxf(v, __shfl_xor(v, 2));
            v = fmaxf(v, __shfl_xor(v, 4));
            v = fmaxf(v, __shfl_xor(v, 8));
            float nm = fmaxf(m_[r], v);
            float alpha = __expf(m_[r] - nm);
            m_[r] = nm;
            lsum[r] *= alpha;
            #pragma unroll
            for (int nt = 0; nt < 4; ++nt) oacc[nt][r] *= alpha;
        }
        #pragma unroll
        for (int nt = 0; nt < 4; ++nt) {
            #pragma unroll
            for (int r = 0; r < 4; ++r) {
                float pv = __expf(sacc[nt][r] - m_[r]);
                lsum[r] += pv;
                const int row = 4 * g + r, col = nt * 16 + c;
                Pw[row * 72 + (((col >> 3) ^ (row & 7))) * 8 + (col & 7)] = f2bf(pv);
            }
        }
        #pragma unroll
        for (int kk = 0; kk < 2; ++kk) {
            bf16x8 pa = *(const bf16x8*)&Pw[c * 72 + (((g + 4 * kk) ^ (c & 7))) * 8];
            #pragma unroll
            for (int nt = 0; nt < 4; ++nt) {
                const int d = nt * 16 + c;
                bf16x8 vb = *(const bf16x8*)&VtS[d * 72 + (((g + 4 * kk) ^ ((d >> 3) & 7))) * 8];
                oacc[nt] = __builtin_amdgcn_mfma_f32_16x16x32_bf16(pa, vb, oacc[nt], 0, 0, 0);
            }
        }
    }

    #pragma unroll
    for (int r = 0; r < 4; ++r) {
        float v = lsum[r];
        v += __shfl_xor(v, 1); v += __shfl_xor(v, 2);
        v += __shfl_xor(v, 4); v += __shfl_xor(v, 8);
        lsum[r] = (v > 0.f) ? 1.0f / v : 0.f;
    }
    #pragma unroll
    for (int nt = 0; nt < 4; ++nt) {
        #pragma unroll
        for (int r = 0; r < 4; ++r) {
            out[((qb + 4 * g + r) * NH + h) * DH + nt * 16 + c] = oacc[nt][r] * lsum[r];
        }
    }
}

extern "C" void kernel_launch(void* const* d_in, const int* in_sizes, int n_in,
                              void* d_out, int out_size, void* d_ws, size_t ws_size,
                              hipStream_t stream) {
    const float* Q    = (const float*)d_in[0];
    const float* K    = (const float*)d_in[1];
    const float* V    = (const float*)d_in[2];
    const void*  mask = d_in[3];
    float* out = (float*)d_out;

    const size_t off_bits = 64;
    const size_t off_qb   = off_bits + (size_t)NWORDS * 8;
    const size_t off_kbz  = off_qb  + (size_t)SEQ * NH * DH * 2;
    const size_t off_vtz  = off_kbz + (size_t)SEQ * NH * DH * 2;
    const size_t need     = off_vtz + (size_t)SEQ * NH * DH * 2;

    if (ws_size >= need) {
        int*      flag = (int*)d_ws;
        uint64_t* bits = (uint64_t*)((char*)d_ws + off_bits);
        ushort*   Qb   = (ushort*)((char*)d_ws + off_qb);
        ushort*   Kbz  = (ushort*)((char*)d_ws + off_kbz);
        ushort*   Vtz  = (ushort*)((char*)d_ws + off_vtz);
        detect_kernel<<<1, 256, 0, stream>>>((const uint32_t*)mask, flag);
        pack_kernel<<<SEQ * SEQ / 256, 256, 0, stream>>>(mask, flag, bits);
        convert_q<<<SEQ * NH * DH / (256 * 8), 256, 0, stream>>>(Q, Qb);
        convert_kv<<<dim3(NKT, NH), 256, 0, stream>>>(K, V, Kbz, Vtz);
        attn8<<<NQB * NH, 256, 0, stream>>>(Qb, Kbz, Vtz, bits, out);
    } else {
        attn_fb<<<dim3(NKT, NH), 256, 0, stream>>>(Q, K, V, (const int*)mask, out);
    }
}